// Round 4
// baseline (52.312 us; speedup 1.0000x reference)
//
#include <hip/hip_runtime.h>

typedef float f32x2 __attribute__((ext_vector_type(2)));
typedef float f32x4 __attribute__((ext_vector_type(4)));

#define H 224
#define W 224
#define HOUT 112
#define P 12544        // 112*112 real pixels per batch
#define PPAD 13312     // 13*1024 (i-side padded)
#define MPB (PPAD/2)   // 6656 j-pair slots per batch
#define NTILES 13      // i-tiles of 1024
#define ITILE 1024
#define JCHUNK 64
#define MCHUNK 32      // JCHUNK/2 packed slots
#define NCHUNKS 196    // real j-chunks: 196*64 = 12544
#define JOBS_PER_BATCH 1300

__device__ __forceinline__ float fast_exp2(float x) {
    return __builtin_amdgcn_exp2f(x);
}

// Packed f32x2 ops: let the compiler select v_pk_fma_f32 / v_pk_add_f32
// (gfx90a+ HasPackedFP32Ops; hand asm in R3 produced operand mixups).
__device__ __forceinline__ f32x2 pk_fma(f32x2 a, f32x2 b, f32x2 c) {
    return __builtin_elementwise_fma(a, b, c);
}
__device__ __forceinline__ f32x2 pk_add(f32x2 a, f32x2 b) {
    return a + b;
}

// j-pair packed records (pair m = pixels 2m, 2m+1):
//   gA[m] = (fx0, fx1, fy0, fy1)   f = rgb/15, nearest-downsampled
//   gB[m] = (fz0, fz1, A0, A1)     A = -0.5*log2e*|f|^2  (pad pixels: A=-1e30)
//   gU[m] = (u0, u1)               u = 2x2-mean of softmax channel-0
__global__ __launch_bounds__(256) void crf_prep(const float* __restrict__ fcams,
                                                const float* __restrict__ img,
                                                f32x4* __restrict__ gA,
                                                f32x4* __restrict__ gB,
                                                f32x2* __restrict__ gU,
                                                float* __restrict__ out) {
    int idx = blockIdx.x * 256 + threadIdx.x;   // [0, 2*MPB)
    if (idx == 0) out[0] = 0.f;                 // replaces hipMemsetAsync node
    int b = idx / MPB;
    int m = idx - b * MPB;
    const float* ib = img + (size_t)b * 3 * H * W;
    const float* cb = fcams + (size_t)b * 2 * H * W;
    float fx[2] = {0.f, 0.f}, fy[2] = {0.f, 0.f}, fz[2] = {0.f, 0.f};
    float Av[2] = {-1e30f, -1e30f}, uv[2] = {0.f, 0.f};
    #pragma unroll
    for (int s = 0; s < 2; ++s) {
        int p = 2 * m + s;
        if (p < P) {
            int y = p / HOUT, x = p - y * HOUT;
            int off = (2 * y) * W + 2 * x;
            const float inv_sigma = 1.0f / 15.0f;
            float a0 = ib[off] * inv_sigma;
            float a1 = ib[H * W + off] * inv_sigma;
            float a2 = ib[2 * H * W + off] * inv_sigma;
            fx[s] = a0; fy[s] = a1; fz[s] = a2;
            Av[s] = -0.72134752044448170f * (a0 * a0 + a1 * a1 + a2 * a2);
            const float l2e = 1.44269504088896340f;
            float ssum = 0.f;
            #pragma unroll
            for (int dy = 0; dy < 2; ++dy) {
                #pragma unroll
                for (int dx = 0; dx < 2; ++dx) {
                    int o = (2 * y + dy) * W + (2 * x + dx);
                    float d = cb[o] - cb[H * W + o];
                    ssum += 1.0f / (1.0f + fast_exp2(-d * l2e));
                }
            }
            uv[s] = 0.25f * ssum;
        }
    }
    f32x4 ra; ra.x = fx[0]; ra.y = fx[1]; ra.z = fy[0]; ra.w = fy[1];
    f32x4 rb; rb.x = fz[0]; rb.y = fz[1]; rb.z = Av[0]; rb.w = Av[1];
    f32x2 ru; ru.x = uv[0]; ru.y = uv[1];
    gA[idx] = ra; gB[idx] = rb; gU[idx] = ru;
}

// Triangular-tiled energy with j-packed f32x2 lanes:
//   per i: S_u = sum_j K_ij*u_j, S_1 = sum_j K_ij; contribution = scale*(p_i*S_u + q_i*S_1)
__global__ __launch_bounds__(256) void crf_energy(const f32x4* __restrict__ gA,
                                                  const f32x4* __restrict__ gB,
                                                  const f32x2* __restrict__ gU,
                                                  float* __restrict__ out) {
    __shared__ f32x4 sA[MCHUNK], sB[MCHUNK];
    __shared__ f32x2 sU[MCHUNK];

    int bid = blockIdx.x;
    int b = bid / JOBS_PER_BATCH;
    int r = bid - b * JOBS_PER_BATCH;
    // decode (it, jc): tile it<12 has 16 ordered + (180-16*it) symmetric jobs; tile 12: 4 ordered
    int it = 0;
    #pragma unroll 1
    for (; it < NTILES; ++it) {
        int cnt = (it < 12) ? (NCHUNKS - 16 * it) : 4;
        if (r < cnt) break;
        r -= cnt;
    }
    int jc = 16 * it + r;
    float scale = (r >= 16) ? 2.0f : 1.0f;

    const f32x4* gAb = gA + (size_t)b * MPB;
    const f32x4* gBb = gB + (size_t)b * MPB;
    const f32x2* gUb = gU + (size_t)b * MPB;

    int t = threadIdx.x;
    if (t < MCHUNK)              sA[t] = gAb[jc * MCHUNK + t];
    else if (t < 2 * MCHUNK)     sB[t - MCHUNK] = gBb[jc * MCHUNK + t - MCHUNK];
    else if (t < 3 * MCHUNK)     sU[t - 2 * MCHUNK] = gUb[jc * MCHUNK + t - 2 * MCHUNK];

    // this thread's 4 i-pixels -> loop-invariant splats
    int m0 = it * (ITILE / 2) + t * 2;
    f32x4 qa0 = gAb[m0], qa1 = gAb[m0 + 1];
    f32x4 qb0 = gBb[m0], qb1 = gBb[m0 + 1];
    f32x2 qu0 = gUb[m0], qu1 = gUb[m0 + 1];
    const float l2e = 1.44269504088896340f;
    float axv[4] = {qa0.x, qa0.y, qa1.x, qa1.y};
    float ayv[4] = {qa0.z, qa0.w, qa1.z, qa1.w};
    float azv[4] = {qb0.x, qb0.y, qb1.x, qb1.y};
    float Aiv[4] = {qb0.z, qb0.w, qb1.z, qb1.w};
    float uiv[4] = {qu0.x, qu0.y, qu1.x, qu1.y};
    f32x2 fxS[4], fyS[4], fzS[4], AiS[4], Su[4], S1[4];
    float piv[4], qiv[4];
    #pragma unroll
    for (int k = 0; k < 4; ++k) {
        fxS[k].x = fxS[k].y = axv[k] * l2e;
        fyS[k].x = fyS[k].y = ayv[k] * l2e;
        fzS[k].x = fzS[k].y = azv[k] * l2e;
        AiS[k].x = AiS[k].y = Aiv[k];
        Su[k].x = Su[k].y = 0.f;
        S1[k].x = S1[k].y = 0.f;
        piv[k] = 2.f * uiv[k] - 1.f;
        qiv[k] = 1.f - uiv[k];
    }
    __syncthreads();

    #pragma unroll 4
    for (int m = 0; m < MCHUNK; ++m) {
        f32x4 a  = sA[m];                                 // wave-uniform broadcast
        f32x4 b4 = sB[m];
        f32x2 u2 = sU[m];
        f32x2 ax2 = __builtin_shufflevector(a, a, 0, 1);
        f32x2 ay2 = __builtin_shufflevector(a, a, 2, 3);
        f32x2 az2 = __builtin_shufflevector(b4, b4, 0, 1);
        f32x2 Aj2 = __builtin_shufflevector(b4, b4, 2, 3);
        #pragma unroll
        for (int k = 0; k < 4; ++k) {
            f32x2 t2 = pk_add(Aj2, AiS[k]);
            t2 = pk_fma(ax2, fxS[k], t2);
            t2 = pk_fma(ay2, fyS[k], t2);
            t2 = pk_fma(az2, fzS[k], t2);
            f32x2 e;
            e.x = fast_exp2(t2.x);
            e.y = fast_exp2(t2.y);
            Su[k] = pk_fma(e, u2, Su[k]);
            S1[k] = pk_add(S1[k], e);
        }
    }

    float tot = 0.f;
    #pragma unroll
    for (int k = 0; k < 4; ++k)
        tot += piv[k] * (Su[k].x + Su[k].y) + qiv[k] * (S1[k].x + S1[k].y);
    tot *= scale;

    #pragma unroll
    for (int o = 32; o > 0; o >>= 1) tot += __shfl_down(tot, o);

    __shared__ float wsum[4];
    int lane = t & 63, wid = t >> 6;
    if (lane == 0) wsum[wid] = tot;
    __syncthreads();
    if (t == 0) {
        atomicAdd(out, -0.5f * ((wsum[0] + wsum[1]) + (wsum[2] + wsum[3])));
    }
}

extern "C" void kernel_launch(void* const* d_in, const int* in_sizes, int n_in,
                              void* d_out, int out_size, void* d_ws, size_t ws_size,
                              hipStream_t stream) {
    const float* fcams = (const float*)d_in[0];   // [2, 2, 224, 224]
    const float* img   = (const float*)d_in[1];   // [2, 3, 224, 224]
    float* out = (float*)d_out;                   // scalar

    char* ws = (char*)d_ws;
    f32x4* gA = (f32x4*)ws;                                   // 2*MPB*16 B = 213 KB
    f32x4* gB = (f32x4*)(ws + (size_t)2 * MPB * 16);          // 213 KB
    f32x2* gU = (f32x2*)(ws + (size_t)4 * MPB * 16);          // 106 KB

    crf_prep<<<(2 * MPB) / 256, 256, 0, stream>>>(fcams, img, gA, gB, gU, out);
    crf_energy<<<2 * JOBS_PER_BATCH, 256, 0, stream>>>(gA, gB, gU, out);
}

// Round 5
// 42.507 us; speedup vs baseline: 1.2307x; 1.2307x over previous
//
#include <hip/hip_runtime.h>

typedef float f32x2 __attribute__((ext_vector_type(2)));
typedef float f32x4 __attribute__((ext_vector_type(4)));

#define H 224
#define W 224
#define HOUT 112
#define P 12544        // 112*112 real pixels per batch
#define PPAD 13312     // 13*1024 (i-side padded)
#define MPB (PPAD/2)   // 6656 j-pair slots per batch
#define NTILES 13      // i-tiles of 1024
#define ITILE 1024
#define JCHUNK 64
#define MCHUNK 32      // JCHUNK/2 packed slots
#define NCHUNKS 196    // real j-chunks: 196*64 = 12544
#define JOBS_PER_BATCH 1300
#define NPART (2 * JOBS_PER_BATCH)

__device__ __forceinline__ float fast_exp2(float x) {
    return __builtin_amdgcn_exp2f(x);
}

// Packed f32x2 ops via compiler ISel (v_pk_fma_f32 / v_pk_add_f32 on gfx950).
__device__ __forceinline__ f32x2 pk_fma(f32x2 a, f32x2 b, f32x2 c) {
    return __builtin_elementwise_fma(a, b, c);
}
__device__ __forceinline__ f32x2 pk_add(f32x2 a, f32x2 b) {
    return a + b;
}

// j-pair packed records (pair m = pixels 2m, 2m+1):
//   gA[m] = (fx0, fx1, fy0, fy1)   f = rgb/15, nearest-downsampled
//   gB[m] = (fz0, fz1, A0, A1)     A = -0.5*log2e*|f|^2  (pad pixels: A=-1e30)
//   gU[m] = (u0, u1)               u = 2x2-mean of softmax channel-0
__global__ __launch_bounds__(256) void crf_prep(const float* __restrict__ fcams,
                                                const float* __restrict__ img,
                                                f32x4* __restrict__ gA,
                                                f32x4* __restrict__ gB,
                                                f32x2* __restrict__ gU) {
    int idx = blockIdx.x * 256 + threadIdx.x;   // [0, 2*MPB)
    int b = idx / MPB;
    int m = idx - b * MPB;
    const float* ib = img + (size_t)b * 3 * H * W;
    const float* cb = fcams + (size_t)b * 2 * H * W;
    float fx[2] = {0.f, 0.f}, fy[2] = {0.f, 0.f}, fz[2] = {0.f, 0.f};
    float Av[2] = {-1e30f, -1e30f}, uv[2] = {0.f, 0.f};
    #pragma unroll
    for (int s = 0; s < 2; ++s) {
        int p = 2 * m + s;
        if (p < P) {
            int y = p / HOUT, x = p - y * HOUT;
            int off = (2 * y) * W + 2 * x;
            const float inv_sigma = 1.0f / 15.0f;
            float a0 = ib[off] * inv_sigma;
            float a1 = ib[H * W + off] * inv_sigma;
            float a2 = ib[2 * H * W + off] * inv_sigma;
            fx[s] = a0; fy[s] = a1; fz[s] = a2;
            Av[s] = -0.72134752044448170f * (a0 * a0 + a1 * a1 + a2 * a2);
            const float l2e = 1.44269504088896340f;
            float ssum = 0.f;
            #pragma unroll
            for (int dy = 0; dy < 2; ++dy) {
                #pragma unroll
                for (int dx = 0; dx < 2; ++dx) {
                    int o = (2 * y + dy) * W + (2 * x + dx);
                    float d = cb[o] - cb[H * W + o];
                    ssum += 1.0f / (1.0f + fast_exp2(-d * l2e));
                }
            }
            uv[s] = 0.25f * ssum;
        }
    }
    f32x4 ra; ra.x = fx[0]; ra.y = fx[1]; ra.z = fy[0]; ra.w = fy[1];
    f32x4 rb; rb.x = fz[0]; rb.y = fz[1]; rb.z = Av[0]; rb.w = Av[1];
    f32x2 ru; ru.x = uv[0]; ru.y = uv[1];
    gA[idx] = ra; gB[idx] = rb; gU[idx] = ru;
}

// Triangular-tiled energy with j-packed f32x2 lanes. Per-block partial sums
// go to partials[bid] (plain store) — NO same-address atomics (they serialize
// across XCDs and dominated R2-R4 wall time).
__global__ __launch_bounds__(256) void crf_energy(const f32x4* __restrict__ gA,
                                                  const f32x4* __restrict__ gB,
                                                  const f32x2* __restrict__ gU,
                                                  float* __restrict__ partials) {
    __shared__ f32x4 sA[MCHUNK], sB[MCHUNK];
    __shared__ f32x2 sU[MCHUNK];

    int bid = blockIdx.x;
    int b = bid / JOBS_PER_BATCH;
    int r = bid - b * JOBS_PER_BATCH;
    // decode (it, jc): tile it<12 has 16 ordered + (180-16*it) symmetric jobs; tile 12: 4 ordered
    int it = 0;
    #pragma unroll 1
    for (; it < NTILES; ++it) {
        int cnt = (it < 12) ? (NCHUNKS - 16 * it) : 4;
        if (r < cnt) break;
        r -= cnt;
    }
    int jc = 16 * it + r;
    float scale = (r >= 16) ? 2.0f : 1.0f;

    const f32x4* gAb = gA + (size_t)b * MPB;
    const f32x4* gBb = gB + (size_t)b * MPB;
    const f32x2* gUb = gU + (size_t)b * MPB;

    int t = threadIdx.x;
    if (t < MCHUNK)              sA[t] = gAb[jc * MCHUNK + t];
    else if (t < 2 * MCHUNK)     sB[t - MCHUNK] = gBb[jc * MCHUNK + t - MCHUNK];
    else if (t < 3 * MCHUNK)     sU[t - 2 * MCHUNK] = gUb[jc * MCHUNK + t - 2 * MCHUNK];

    // this thread's 4 i-pixels -> loop-invariant splats
    int m0 = it * (ITILE / 2) + t * 2;
    f32x4 qa0 = gAb[m0], qa1 = gAb[m0 + 1];
    f32x4 qb0 = gBb[m0], qb1 = gBb[m0 + 1];
    f32x2 qu0 = gUb[m0], qu1 = gUb[m0 + 1];
    const float l2e = 1.44269504088896340f;
    float axv[4] = {qa0.x, qa0.y, qa1.x, qa1.y};
    float ayv[4] = {qa0.z, qa0.w, qa1.z, qa1.w};
    float azv[4] = {qb0.x, qb0.y, qb1.x, qb1.y};
    float Aiv[4] = {qb0.z, qb0.w, qb1.z, qb1.w};
    float uiv[4] = {qu0.x, qu0.y, qu1.x, qu1.y};
    f32x2 fxS[4], fyS[4], fzS[4], AiS[4], Su[4], S1[4];
    float piv[4], qiv[4];
    #pragma unroll
    for (int k = 0; k < 4; ++k) {
        fxS[k].x = fxS[k].y = axv[k] * l2e;
        fyS[k].x = fyS[k].y = ayv[k] * l2e;
        fzS[k].x = fzS[k].y = azv[k] * l2e;
        AiS[k].x = AiS[k].y = Aiv[k];
        Su[k].x = Su[k].y = 0.f;
        S1[k].x = S1[k].y = 0.f;
        piv[k] = 2.f * uiv[k] - 1.f;
        qiv[k] = 1.f - uiv[k];
    }
    __syncthreads();

    #pragma unroll 4
    for (int m = 0; m < MCHUNK; ++m) {
        f32x4 a  = sA[m];                                 // wave-uniform broadcast
        f32x4 b4 = sB[m];
        f32x2 u2 = sU[m];
        f32x2 ax2 = __builtin_shufflevector(a, a, 0, 1);
        f32x2 ay2 = __builtin_shufflevector(a, a, 2, 3);
        f32x2 az2 = __builtin_shufflevector(b4, b4, 0, 1);
        f32x2 Aj2 = __builtin_shufflevector(b4, b4, 2, 3);
        #pragma unroll
        for (int k = 0; k < 4; ++k) {
            f32x2 t2 = pk_add(Aj2, AiS[k]);
            t2 = pk_fma(ax2, fxS[k], t2);
            t2 = pk_fma(ay2, fyS[k], t2);
            t2 = pk_fma(az2, fzS[k], t2);
            f32x2 e;
            e.x = fast_exp2(t2.x);
            e.y = fast_exp2(t2.y);
            Su[k] = pk_fma(e, u2, Su[k]);
            S1[k] = pk_add(S1[k], e);
        }
    }

    float tot = 0.f;
    #pragma unroll
    for (int k = 0; k < 4; ++k)
        tot += piv[k] * (Su[k].x + Su[k].y) + qiv[k] * (S1[k].x + S1[k].y);
    tot *= scale;

    #pragma unroll
    for (int o = 32; o > 0; o >>= 1) tot += __shfl_down(tot, o);

    __shared__ float wsum[4];
    int lane = t & 63, wid = t >> 6;
    if (lane == 0) wsum[wid] = tot;
    __syncthreads();
    if (t == 0) {
        partials[bid] = (wsum[0] + wsum[1]) + (wsum[2] + wsum[3]);
    }
}

// Single-block final reduction: out = -0.5 * sum(partials)
__global__ __launch_bounds__(256) void crf_reduce(const float* __restrict__ partials,
                                                  float* __restrict__ out) {
    int t = threadIdx.x;
    float s = 0.f;
    for (int i = t; i < NPART; i += 256) s += partials[i];
    #pragma unroll
    for (int o = 32; o > 0; o >>= 1) s += __shfl_down(s, o);
    __shared__ float wsum[4];
    int lane = t & 63, wid = t >> 6;
    if (lane == 0) wsum[wid] = s;
    __syncthreads();
    if (t == 0) out[0] = -0.5f * ((wsum[0] + wsum[1]) + (wsum[2] + wsum[3]));
}

extern "C" void kernel_launch(void* const* d_in, const int* in_sizes, int n_in,
                              void* d_out, int out_size, void* d_ws, size_t ws_size,
                              hipStream_t stream) {
    const float* fcams = (const float*)d_in[0];   // [2, 2, 224, 224]
    const float* img   = (const float*)d_in[1];   // [2, 3, 224, 224]
    float* out = (float*)d_out;                   // scalar

    char* ws = (char*)d_ws;
    f32x4* gA = (f32x4*)ws;                                   // 2*MPB*16 B = 213 KB
    f32x4* gB = (f32x4*)(ws + (size_t)2 * MPB * 16);          // 213 KB
    f32x2* gU = (f32x2*)(ws + (size_t)4 * MPB * 16);          // 106 KB
    float* partials = (float*)(ws + (size_t)4 * MPB * 16 + (size_t)2 * MPB * 8); // 10.4 KB

    crf_prep<<<(2 * MPB) / 256, 256, 0, stream>>>(fcams, img, gA, gB, gU);
    crf_energy<<<NPART, 256, 0, stream>>>(gA, gB, gU, partials);
    crf_reduce<<<1, 256, 0, stream>>>(partials, out);
}